// Round 10
// baseline (132.139 us; speedup 1.0000x reference)
//
#include <hip/hip_runtime.h>
#include <hip/hip_bf16.h>
#include <math.h>

#define NROWS 8192
#define DIM 128
#define BM 128
#define BN 128
#define NRB 64                         // 64 row/col blocks of 128
#define CHW 4                          // tiles per block (chunk width)
#define NCH 16                         // max chunks per row-strip
#define CS 8                           // fallback slab count
#define COLS_PER_SLAB (NROWS / CS)
#define CT_ITERS (COLS_PER_SLAB / BN)
#define SCALE 1.69864368f              // sqrt(2 * log2(e)) -> acc u = sim*log2(e)
#define LN2F 0.69314718056f

typedef __attribute__((ext_vector_type(8))) short bf16x8;
typedef __attribute__((ext_vector_type(4))) float f32x4;

// ---------------- normalize rows -> bf16 * SCALE; zero losssum[0] ----------------
__global__ __launch_bounds__(256) void k_norm(const float* __restrict__ f,
                                              __hip_bfloat16* __restrict__ fnb,
                                              float* __restrict__ losssum) {
  if (blockIdx.x == 0 && threadIdx.x == 0) losssum[0] = 0.f;
  int wave = threadIdx.x >> 6;
  int lane = threadIdx.x & 63;
  int row = blockIdx.x * 4 + wave;
  const float* src = f + (size_t)row * DIM;
  float v0 = src[lane];
  float v1 = src[lane + 64];
  float ss = v0 * v0 + v1 * v1;
#pragma unroll
  for (int o = 32; o > 0; o >>= 1) ss += __shfl_down(ss, o);
  ss = __shfl(ss, 0);
  float inv = SCALE / fmaxf(sqrtf(ss), 1e-8f);
  __hip_bfloat16* dst = fnb + (size_t)row * DIM;
  dst[lane] = __float2bfloat16(v0 * inv);
  dst[lane + 64] = __float2bfloat16(v1 * inv);
}

// ================= TRIANGULAR PATH =================
// Block (c=blockIdx.x, bi=blockIdx.y): tiles (bi, bj), bj = bi+4c+e, e=0..3, bj<64.
// Row stats (rows of bi) accumulate across the strip -> Prow[c][row][3].
// Col stats (rows of bj, = transposed pairs) -> atomicAdd Pcol[64-d][col][3], d=bj-bi>0.
__global__ __launch_bounds__(256, 2) void k_main_tri(
    const ushort* __restrict__ fnb, const int* __restrict__ lab,
    float* __restrict__ Prow, float* __restrict__ Pcol) {
  const int c = blockIdx.x;
  const int bi = blockIdx.y;
  const int bj0 = bi + c * CHW;
  if (bj0 >= NRB) return;

  __shared__ char lds[BM * 256 + BN * 256];
  char* Alds = lds;
  char* Blds = lds + BM * 256;

  const int t = threadIdx.x;
  const int lane = t & 63;
  const int w = t >> 6;
  const int wm = w >> 1, wn = w & 1;
  const int g = lane >> 4, li16 = lane & 15;
  const int i0 = bi * BM;

  // stage A once (swizzled)
  {
    const int4* src = reinterpret_cast<const int4*>(fnb + (size_t)i0 * DIM);
#pragma unroll
    for (int it = 0; it < 8; ++it) {
      int q = t + 256 * it;
      int row = q >> 4, cc = q & 15;
      int4 v = src[q];
      *reinterpret_cast<int4*>(Alds + row * 256 + ((cc << 4) ^ ((row & 7) << 4))) = v;
    }
  }

  int lr[4][4];
#pragma unroll
  for (int m = 0; m < 4; ++m)
#pragma unroll
    for (int r = 0; r < 4; ++r)
      lr[m][r] = lab[i0 + wm * 64 + m * 16 + g * 4 + r];

  float a_tot[4][4] = {}, a_pos[4][4] = {}, a_sim[4][4] = {};

#pragma unroll 1
  for (int bj = bj0; bj < bj0 + CHW && bj < NRB; ++bj) {
    const int j0 = bj * BN;
    const int d = bj - bi;
    __syncthreads();  // prev tile's Blds readers done
    {
      const int4* src = reinterpret_cast<const int4*>(fnb + (size_t)j0 * DIM);
#pragma unroll
      for (int it = 0; it < 8; ++it) {
        int q = t + 256 * it;
        int row = q >> 4, cc = q & 15;
        int4 v = src[q];
        *reinterpret_cast<int4*>(Blds + row * 256 + ((cc << 4) ^ ((row & 7) << 4))) = v;
      }
    }
    __syncthreads();

    f32x4 acc[4][4];
#pragma unroll
    for (int m = 0; m < 4; ++m)
#pragma unroll
      for (int n = 0; n < 4; ++n) acc[m][n] = (f32x4){0.f, 0.f, 0.f, 0.f};

#pragma unroll
    for (int ks = 0; ks < 4; ++ks) {
      const int kb = ks * 64 + (g << 4);
      bf16x8 af[4], bf[4];
#pragma unroll
      for (int m = 0; m < 4; ++m) {
        int r = wm * 64 + m * 16 + li16;
        af[m] = *reinterpret_cast<const bf16x8*>(Alds + r * 256 + (kb ^ ((r & 7) << 4)));
      }
#pragma unroll
      for (int n = 0; n < 4; ++n) {
        int r = wn * 64 + n * 16 + li16;
        bf[n] = *reinterpret_cast<const bf16x8*>(Blds + r * 256 + (kb ^ ((r & 7) << 4)));
      }
#pragma unroll
      for (int m = 0; m < 4; ++m)
#pragma unroll
        for (int n = 0; n < 4; ++n)
          acc[m][n] = __builtin_amdgcn_mfma_f32_16x16x32_bf16(af[m], bf[n], acc[m][n], 0, 0, 0);
    }

    // epilogue: u = acc = sim*log2e; E = 2^u = exp(sim)
    float c_tot[4] = {}, c_pos[4] = {}, c_sim[4] = {};
#pragma unroll
    for (int n = 0; n < 4; ++n) {
      const int lc = lab[j0 + wn * 64 + n * 16 + li16];
#pragma unroll
      for (int m = 0; m < 4; ++m)
#pragma unroll
        for (int r = 0; r < 4; ++r) {
          float u = acc[m][n][r];
          float E = __builtin_exp2f(u);
          float msk = (lr[m][r] == lc) ? 1.f : 0.f;
          a_tot[m][r] += E;
          c_tot[n] += E;
          a_pos[m][r] = fmaf(msk, E, a_pos[m][r]);
          a_sim[m][r] = fmaf(msk, u, a_sim[m][r]);
          c_pos[n] = fmaf(msk, E, c_pos[n]);
          c_sim[n] = fmaf(msk, u, c_sim[n]);
        }
    }

    if (d > 0) {
      // reduce col stats across the 4 g-groups (rows), then 2-way atomic combine (wm)
#pragma unroll
      for (int n = 0; n < 4; ++n) {
        c_tot[n] += __shfl_xor(c_tot[n], 16); c_tot[n] += __shfl_xor(c_tot[n], 32);
        c_pos[n] += __shfl_xor(c_pos[n], 16); c_pos[n] += __shfl_xor(c_pos[n], 32);
        c_sim[n] += __shfl_xor(c_sim[n], 16); c_sim[n] += __shfl_xor(c_sim[n], 32);
      }
      if (g == 0) {
        const int s = NRB - d;
#pragma unroll
        for (int n = 0; n < 4; ++n) {
          int col = j0 + wn * 64 + n * 16 + li16;
          float* dst = Pcol + ((size_t)s * NROWS + col) * 3;
          atomicAdd(&dst[0], c_tot[n]);
          atomicAdd(&dst[1], c_pos[n]);
          atomicAdd(&dst[2], c_sim[n]);
        }
      }
    }
  }

  // row reduce across the 16 li16 lanes (cols)
#pragma unroll
  for (int m = 0; m < 4; ++m)
#pragma unroll
    for (int r = 0; r < 4; ++r)
#pragma unroll
      for (int off = 8; off > 0; off >>= 1) {
        a_tot[m][r] += __shfl_xor(a_tot[m][r], off);
        a_pos[m][r] += __shfl_xor(a_pos[m][r], off);
        a_sim[m][r] += __shfl_xor(a_sim[m][r], off);
      }

  __syncthreads();
  float* red = reinterpret_cast<float*>(lds);  // [128][2][3]
  if (li16 == 0) {
#pragma unroll
    for (int m = 0; m < 4; ++m)
#pragma unroll
      for (int r = 0; r < 4; ++r) {
        int rl = wm * 64 + m * 16 + g * 4 + r;
        red[(rl * 2 + wn) * 3 + 0] = a_tot[m][r];
        red[(rl * 2 + wn) * 3 + 1] = a_pos[m][r];
        red[(rl * 2 + wn) * 3 + 2] = a_sim[m][r];
      }
  }
  __syncthreads();
  if (wn == 0 && li16 == 0) {
#pragma unroll
    for (int m = 0; m < 4; ++m)
#pragma unroll
      for (int r = 0; r < 4; ++r) {
        int rl = wm * 64 + m * 16 + g * 4 + r;
        float* dst = Prow + ((size_t)c * NROWS + (i0 + rl)) * 3;
        dst[0] = red[(rl * 2) * 3 + 0] + red[(rl * 2 + 1) * 3 + 0];
        dst[1] = red[(rl * 2) * 3 + 1] + red[(rl * 2 + 1) * 3 + 1];
        dst[2] = red[(rl * 2) * 3 + 2] + red[(rl * 2 + 1) * 3 + 2];
      }
  }
}

__global__ __launch_bounds__(1024) void k_rowfinal_tri(
    const float* __restrict__ Prow, const float* __restrict__ Pcol,
    const int* __restrict__ lab, float* __restrict__ losssum) {
  __shared__ int sh[16][16];
  __shared__ int hist_s[16];
  __shared__ float sred[1024];
  const int t = threadIdx.x;
  const int w = t >> 6;
  if ((t & 63) < 16) sh[w][t & 63] = 0;
  __syncthreads();
#pragma unroll
  for (int it = 0; it < NROWS / 1024; ++it)
    atomicAdd(&sh[w][lab[t + it * 1024]], 1);
  __syncthreads();
  if (t < 16) {
    int s = 0;
#pragma unroll
    for (int x = 0; x < 16; ++x) s += sh[x][t];
    hist_s[t] = s;
  }
  __syncthreads();

  int i = blockIdx.x * 1024 + t;
  int b = i >> 7;
  int cmax = (63 - b) >> 2;
  float st = 0.f, sp = 0.f, sa = 0.f;
  for (int cc = 0; cc <= cmax; ++cc) {
    const float* p = Prow + ((size_t)cc * NROWS + i) * 3;
    st += p[0]; sp += p[1]; sa += p[2];
  }
  for (int s = 0; s < NRB; ++s) {  // unwritten slots are memset-zero
    const float* p = Pcol + ((size_t)s * NROWS + i) * 3;
    st += p[0]; sp += p[1]; sa += p[2];
  }
  float cnt = (float)hist_s[lab[i]];
  float negtot = st - sp + cnt;
  float li = cnt * logf(negtot) + sp / negtot - LN2F * sa;
  sred[t] = li;
  __syncthreads();
  for (int s2 = 512; s2 > 0; s2 >>= 1) {
    if (t < s2) sred[t] += sred[t + s2];
    __syncthreads();
  }
  if (t == 0) {
    atomicAdd(&losssum[0], sred[0]);
    if (blockIdx.x == 0) {
      int np = 0;
#pragma unroll
      for (int cq = 0; cq < 10; ++cq) np += hist_s[cq] * hist_s[cq];
      losssum[1] = (float)np;
    }
  }
}

// ================= FALLBACK SLAB PATH (small ws) =================
__global__ __launch_bounds__(256, 2) void k_main_slab(
    const ushort* __restrict__ fnb, const int* __restrict__ lab, float* __restrict__ P) {
  __shared__ char lds[BM * 256 + BN * 256];
  char* Alds = lds;
  char* Blds = lds + BM * 256;
  const int t = threadIdx.x;
  const int lane = t & 63;
  const int w = t >> 6;
  const int wm = w >> 1, wn = w & 1;
  const int g = lane >> 4, li16 = lane & 15;
  const int cs = blockIdx.x;
  const int i0 = blockIdx.y * BM;
  {
    const int4* src = reinterpret_cast<const int4*>(fnb + (size_t)i0 * DIM);
#pragma unroll
    for (int it = 0; it < 8; ++it) {
      int q = t + 256 * it;
      int row = q >> 4, cc = q & 15;
      int4 v = src[q];
      *reinterpret_cast<int4*>(Alds + row * 256 + ((cc << 4) ^ ((row & 7) << 4))) = v;
    }
  }
  int lr[4][4];
#pragma unroll
  for (int m = 0; m < 4; ++m)
#pragma unroll
    for (int r = 0; r < 4; ++r)
      lr[m][r] = lab[i0 + wm * 64 + m * 16 + g * 4 + r];
  float a_tot[4][4] = {}, a_pos[4][4] = {}, a_sim[4][4] = {};
  for (int ct = 0; ct < CT_ITERS; ++ct) {
    const int j0 = cs * COLS_PER_SLAB + ct * BN;
    __syncthreads();
    {
      const int4* src = reinterpret_cast<const int4*>(fnb + (size_t)j0 * DIM);
#pragma unroll
      for (int it = 0; it < 8; ++it) {
        int q = t + 256 * it;
        int row = q >> 4, cc = q & 15;
        int4 v = src[q];
        *reinterpret_cast<int4*>(Blds + row * 256 + ((cc << 4) ^ ((row & 7) << 4))) = v;
      }
    }
    __syncthreads();
    f32x4 acc[4][4];
#pragma unroll
    for (int m = 0; m < 4; ++m)
#pragma unroll
      for (int n = 0; n < 4; ++n) acc[m][n] = (f32x4){0.f, 0.f, 0.f, 0.f};
#pragma unroll
    for (int ks = 0; ks < 4; ++ks) {
      const int kb = ks * 64 + (g << 4);
      bf16x8 af[4], bf[4];
#pragma unroll
      for (int m = 0; m < 4; ++m) {
        int r = wm * 64 + m * 16 + li16;
        af[m] = *reinterpret_cast<const bf16x8*>(Alds + r * 256 + (kb ^ ((r & 7) << 4)));
      }
#pragma unroll
      for (int n = 0; n < 4; ++n) {
        int r = wn * 64 + n * 16 + li16;
        bf[n] = *reinterpret_cast<const bf16x8*>(Blds + r * 256 + (kb ^ ((r & 7) << 4)));
      }
#pragma unroll
      for (int m = 0; m < 4; ++m)
#pragma unroll
        for (int n = 0; n < 4; ++n)
          acc[m][n] = __builtin_amdgcn_mfma_f32_16x16x32_bf16(af[m], bf[n], acc[m][n], 0, 0, 0);
    }
#pragma unroll
    for (int n = 0; n < 4; ++n) {
      const int lc = lab[j0 + wn * 64 + n * 16 + li16];
#pragma unroll
      for (int m = 0; m < 4; ++m)
#pragma unroll
        for (int r = 0; r < 4; ++r) {
          float u = acc[m][n][r];
          float E = __builtin_exp2f(u);
          float msk = (lr[m][r] == lc) ? 1.f : 0.f;
          a_tot[m][r] += E;
          a_pos[m][r] = fmaf(msk, E, a_pos[m][r]);
          a_sim[m][r] = fmaf(msk, u, a_sim[m][r]);
        }
    }
  }
#pragma unroll
  for (int m = 0; m < 4; ++m)
#pragma unroll
    for (int r = 0; r < 4; ++r)
#pragma unroll
      for (int off = 8; off > 0; off >>= 1) {
        a_tot[m][r] += __shfl_xor(a_tot[m][r], off);
        a_pos[m][r] += __shfl_xor(a_pos[m][r], off);
        a_sim[m][r] += __shfl_xor(a_sim[m][r], off);
      }
  __syncthreads();
  float* red = reinterpret_cast<float*>(lds);
  if (li16 == 0) {
#pragma unroll
    for (int m = 0; m < 4; ++m)
#pragma unroll
      for (int r = 0; r < 4; ++r) {
        int rl = wm * 64 + m * 16 + g * 4 + r;
        red[(rl * 2 + wn) * 3 + 0] = a_tot[m][r];
        red[(rl * 2 + wn) * 3 + 1] = a_pos[m][r];
        red[(rl * 2 + wn) * 3 + 2] = a_sim[m][r];
      }
  }
  __syncthreads();
  if (wn == 0 && li16 == 0) {
#pragma unroll
    for (int m = 0; m < 4; ++m)
#pragma unroll
      for (int r = 0; r < 4; ++r) {
        int rl = wm * 64 + m * 16 + g * 4 + r;
        float* dst = P + ((size_t)cs * NROWS + (i0 + rl)) * 3;
        dst[0] = red[(rl * 2) * 3 + 0] + red[(rl * 2 + 1) * 3 + 0];
        dst[1] = red[(rl * 2) * 3 + 1] + red[(rl * 2 + 1) * 3 + 1];
        dst[2] = red[(rl * 2) * 3 + 2] + red[(rl * 2 + 1) * 3 + 2];
      }
  }
}

__global__ __launch_bounds__(1024) void k_rowfinal_slab(
    const float* __restrict__ P, const int* __restrict__ lab, float* __restrict__ losssum) {
  __shared__ int sh[16][16];
  __shared__ int hist_s[16];
  __shared__ float sred[1024];
  const int t = threadIdx.x;
  const int w = t >> 6;
  if ((t & 63) < 16) sh[w][t & 63] = 0;
  __syncthreads();
#pragma unroll
  for (int it = 0; it < NROWS / 1024; ++it)
    atomicAdd(&sh[w][lab[t + it * 1024]], 1);
  __syncthreads();
  if (t < 16) {
    int s = 0;
#pragma unroll
    for (int x = 0; x < 16; ++x) s += sh[x][t];
    hist_s[t] = s;
  }
  __syncthreads();
  int i = blockIdx.x * 1024 + t;
  float st = 0.f, sp = 0.f, sa = 0.f;
#pragma unroll
  for (int cs = 0; cs < CS; ++cs) {
    const float* p = P + ((size_t)cs * NROWS + i) * 3;
    st += p[0]; sp += p[1]; sa += p[2];
  }
  float cnt = (float)hist_s[lab[i]];
  float negtot = st - sp + cnt;
  float li = cnt * logf(negtot) + sp / negtot - LN2F * sa;
  sred[t] = li;
  __syncthreads();
  for (int s2 = 512; s2 > 0; s2 >>= 1) {
    if (t < s2) sred[t] += sred[t + s2];
    __syncthreads();
  }
  if (t == 0) {
    atomicAdd(&losssum[0], sred[0]);
    if (blockIdx.x == 0) {
      int np = 0;
#pragma unroll
      for (int cq = 0; cq < 10; ++cq) np += hist_s[cq] * hist_s[cq];
      losssum[1] = (float)np;
    }
  }
}

// ---------------- output ----------------
__global__ void k_out(const float* __restrict__ losssum, float* __restrict__ out) {
  if (threadIdx.x == 0) out[0] = losssum[0] / losssum[1];
}

extern "C" void kernel_launch(void* const* d_in, const int* in_sizes, int n_in,
                              void* d_out, int out_size, void* d_ws, size_t ws_size,
                              hipStream_t stream) {
  const float* feat = (const float*)d_in[0];
  const int* lab = (const int*)d_in[1];
  float* out = (float*)d_out;
  char* ws = (char*)d_ws;

  const size_t fnbB = (size_t)NROWS * DIM * 2;            // 2 MiB
  const size_t prowB = (size_t)NCH * NROWS * 3 * 4;       // 1.5 MiB
  const size_t pcolB = (size_t)NRB * NROWS * 3 * 4;       // 6 MiB
  __hip_bfloat16* fnb = (__hip_bfloat16*)ws;

  if (ws_size >= fnbB + prowB + pcolB + 256) {
    float* Prow = (float*)(ws + fnbB);
    float* Pcol = (float*)(ws + fnbB + prowB);
    float* losssum = (float*)(ws + fnbB + prowB + pcolB);
    hipMemsetAsync(Pcol, 0, pcolB, stream);
    k_norm<<<NROWS / 4, 256, 0, stream>>>(feat, fnb, losssum);
    k_main_tri<<<dim3(NCH, NRB), 256, 0, stream>>>((const ushort*)fnb, lab, Prow, Pcol);
    k_rowfinal_tri<<<NROWS / 1024, 1024, 0, stream>>>(Prow, Pcol, lab, losssum);
    k_out<<<1, 64, 0, stream>>>(losssum, out);
  } else {
    float* P = (float*)(ws + fnbB);                       // [CS][NROWS][3]
    float* losssum = (float*)(ws + fnbB + (size_t)CS * NROWS * 3 * 4);
    k_norm<<<NROWS / 4, 256, 0, stream>>>(feat, fnb, losssum);
    k_main_slab<<<dim3(CS, NROWS / BM), 256, 0, stream>>>((const ushort*)fnb, lab, P);
    k_rowfinal_slab<<<NROWS / 1024, 1024, 0, stream>>>(P, lab, losssum);
    k_out<<<1, 64, 0, stream>>>(losssum, out);
  }
}

// Round 11
// 62.447 us; speedup vs baseline: 2.1160x; 2.1160x over previous
//
#include <hip/hip_runtime.h>
#include <hip/hip_bf16.h>
#include <math.h>

#define NROWS 8192
#define DIM 128
#define BM 128
#define BN 128
#define CS 8
#define COLS_PER_SLAB (NROWS / CS)     // 1024
#define CT_ITERS (COLS_PER_SLAB / BN)  // 8
#define RS (NROWS / BM)                // 64
#define SCALE 1.69864368f              // sqrt(2*log2(e)) -> acc u = sim*log2(e)
#define LN2F 0.69314718056f

typedef __attribute__((ext_vector_type(8))) short bf16x8;
typedef __attribute__((ext_vector_type(4))) float f32x4;

__device__ __forceinline__ void gload16(const void* g, void* l) {
  __builtin_amdgcn_global_load_lds(
      (const __attribute__((address_space(1))) void*)g,
      (__attribute__((address_space(3))) void*)l, 16, 0, 0);
}

// stage a 128x128 bf16 tile (global rows row0..+127) into LDS `tile`:
// linear LDS dest (gload_lds requirement), inverse-swizzled GLOBAL source,
// swizzle chunk ^= (row&7) (involution; reads apply the same XOR).
// wave w covers tile rows [w*32, +32): 8 issues x 1024B.
__device__ __forceinline__ void stage_tile(const ushort* __restrict__ fnb, int row0,
                                           char* tile, int w, int lane) {
  const char* gb = reinterpret_cast<const char*>(fnb);
#pragma unroll
  for (int i = 0; i < 8; ++i) {
    int rl = w * 32 + i * 4 + (lane >> 4);    // row within tile (row0 % 128 == 0)
    int src = ((lane & 15) ^ (rl & 7)) << 4;  // source chunk byte offset
    gload16(gb + (size_t)(row0 + rl) * 256 + src, tile + w * 8192 + i * 1024);
  }
}

// ---------------- normalize rows -> bf16 * SCALE; zero losssum[0] ----------------
__global__ __launch_bounds__(256) void k_norm(const float* __restrict__ f,
                                              __hip_bfloat16* __restrict__ fnb,
                                              float* __restrict__ losssum) {
  if (blockIdx.x == 0 && threadIdx.x == 0) losssum[0] = 0.f;
  int wave = threadIdx.x >> 6;
  int lane = threadIdx.x & 63;
  int row = blockIdx.x * 4 + wave;
  const float* src = f + (size_t)row * DIM;
  float v0 = src[lane];
  float v1 = src[lane + 64];
  float ss = v0 * v0 + v1 * v1;
#pragma unroll
  for (int o = 32; o > 0; o >>= 1) ss += __shfl_down(ss, o);
  ss = __shfl(ss, 0);
  float inv = SCALE / fmaxf(sqrtf(ss), 1e-8f);
  __hip_bfloat16* dst = fnb + (size_t)row * DIM;
  dst[lane] = __float2bfloat16(v0 * inv);
  dst[lane + 64] = __float2bfloat16(v1 * inv);
}

// ---------------- MFMA pass: slab grid (cs, bi), pipelined gload_lds staging ----
// LDS: lds[0..32K) = A tile then B(odd); lds[32K..64K) = B(even).
// A fragments live in registers for the whole kernel.
__global__ __launch_bounds__(256, 2) void k_main(
    const ushort* __restrict__ fnb, const int* __restrict__ lab,
    float* __restrict__ P) {
  __shared__ char lds[2 * BM * 256];  // 64 KB
  const int t = threadIdx.x;
  const int lane = t & 63;
  const int w = t >> 6;
  const int wm = w >> 1, wn = w & 1;
  const int g = lane >> 4, li16 = lane & 15;
  const int cs = blockIdx.x;
  const int i0 = blockIdx.y * BM;
  const int jslab = cs * COLS_PER_SLAB;

  // prologue: stage A -> lds[0], B0 -> lds[32K]
  stage_tile(fnb, i0, lds, w, lane);
  stage_tile(fnb, jslab, lds + 32768, w, lane);
  asm volatile("s_waitcnt vmcnt(8)" ::: "memory");  // A's 8 oldest done; B0 in flight
  __builtin_amdgcn_s_barrier();

  // A fragments -> registers (rows wm*64+m*16+li16, chunks ks*4+g, swizzled)
  bf16x8 af[4][4];
#pragma unroll
  for (int m = 0; m < 4; ++m) {
    int r = wm * 64 + m * 16 + li16;
#pragma unroll
    for (int ks = 0; ks < 4; ++ks) {
      int cb = ((ks * 4 + g) ^ (r & 7)) << 4;
      af[m][ks] = *reinterpret_cast<const bf16x8*>(lds + r * 256 + cb);
    }
  }
  asm volatile("s_waitcnt lgkmcnt(0)" ::: "memory");
  __builtin_amdgcn_sched_barrier(0);
  __builtin_amdgcn_s_barrier();  // all waves done reading A region before B1 lands

  // labels of this thread's C rows: row = wm*64 + m*16 + g*4 + r
  int lr[4][4];
#pragma unroll
  for (int m = 0; m < 4; ++m)
#pragma unroll
    for (int r = 0; r < 4; ++r)
      lr[m][r] = lab[i0 + wm * 64 + m * 16 + g * 4 + r];

  float a_tot[4][4] = {}, a_pos[4][4] = {}, a_sim[4][4] = {};

#pragma unroll 1
  for (int ct = 0; ct < CT_ITERS; ++ct) {
    const int j0 = jslab + ct * BN;
    char* bufc = lds + ((size_t)((ct & 1) ^ 1) << 15);  // B(ct)
    if (ct < CT_ITERS - 1)
      stage_tile(fnb, j0 + BN, lds + ((size_t)(ct & 1) << 15), w, lane);  // B(ct+1)

    f32x4 acc[4][4];
#pragma unroll
    for (int m = 0; m < 4; ++m)
#pragma unroll
      for (int n = 0; n < 4; ++n) acc[m][n] = (f32x4){0.f, 0.f, 0.f, 0.f};

#pragma unroll
    for (int ks = 0; ks < 4; ++ks) {
      bf16x8 bf[4];
#pragma unroll
      for (int n = 0; n < 4; ++n) {
        int r = wn * 64 + n * 16 + li16;
        int cb = ((ks * 4 + g) ^ (r & 7)) << 4;
        bf[n] = *reinterpret_cast<const bf16x8*>(bufc + r * 256 + cb);
      }
#pragma unroll
      for (int m = 0; m < 4; ++m)
#pragma unroll
        for (int n = 0; n < 4; ++n)
          acc[m][n] = __builtin_amdgcn_mfma_f32_16x16x32_bf16(af[m][ks], bf[n], acc[m][n], 0, 0, 0);
    }

    // epilogue: u = sim*log2e; E = 2^u = exp(sim)  (covers the in-flight stage loads)
#pragma unroll
    for (int n = 0; n < 4; ++n) {
      const int lc = lab[j0 + wn * 64 + n * 16 + li16];
#pragma unroll
      for (int m = 0; m < 4; ++m)
#pragma unroll
        for (int r = 0; r < 4; ++r) {
          float u = acc[m][n][r];
          float E = __builtin_exp2f(u);
          float msk = (lr[m][r] == lc) ? 1.f : 0.f;
          a_tot[m][r] += E;
          a_pos[m][r] = fmaf(msk, E, a_pos[m][r]);
          a_sim[m][r] = fmaf(msk, u, a_sim[m][r]);
        }
    }

    asm volatile("s_waitcnt vmcnt(0)" ::: "memory");  // next tile landed (covered)
    __builtin_amdgcn_s_barrier();
  }

  // reduce across the 16 li16 lanes (cols)
#pragma unroll
  for (int m = 0; m < 4; ++m)
#pragma unroll
    for (int r = 0; r < 4; ++r)
#pragma unroll
      for (int off = 8; off > 0; off >>= 1) {
        a_tot[m][r] += __shfl_xor(a_tot[m][r], off);
        a_pos[m][r] += __shfl_xor(a_pos[m][r], off);
        a_sim[m][r] += __shfl_xor(a_sim[m][r], off);
      }

  __syncthreads();  // tiles done; reuse LDS as scratch
  float* red = reinterpret_cast<float*>(lds);  // [128][2][3]
  if (li16 == 0) {
#pragma unroll
    for (int m = 0; m < 4; ++m)
#pragma unroll
      for (int r = 0; r < 4; ++r) {
        int rl = wm * 64 + m * 16 + g * 4 + r;
        red[(rl * 2 + wn) * 3 + 0] = a_tot[m][r];
        red[(rl * 2 + wn) * 3 + 1] = a_pos[m][r];
        red[(rl * 2 + wn) * 3 + 2] = a_sim[m][r];
      }
  }
  __syncthreads();
  if (wn == 0 && li16 == 0) {
#pragma unroll
    for (int m = 0; m < 4; ++m)
#pragma unroll
      for (int r = 0; r < 4; ++r) {
        int rl = wm * 64 + m * 16 + g * 4 + r;
        float* dst = P + ((size_t)cs * NROWS + (i0 + rl)) * 3;
        dst[0] = red[(rl * 2) * 3 + 0] + red[(rl * 2 + 1) * 3 + 0];
        dst[1] = red[(rl * 2) * 3 + 1] + red[(rl * 2 + 1) * 3 + 1];
        dst[2] = red[(rl * 2) * 3 + 2] + red[(rl * 2 + 1) * 3 + 2];
      }
  }
}

// ---------------- per-row finalize + global sum (in-LDS hist) ----------------
__global__ __launch_bounds__(1024) void k_rowfinal(
    const float* __restrict__ P, const int* __restrict__ lab,
    float* __restrict__ losssum) {
  __shared__ int sh[16][16];
  __shared__ int hist_s[16];
  __shared__ float sred[1024];
  const int t = threadIdx.x;
  const int w = t >> 6;
  if ((t & 63) < 16) sh[w][t & 63] = 0;
  __syncthreads();
#pragma unroll
  for (int it = 0; it < NROWS / 1024; ++it)
    atomicAdd(&sh[w][lab[t + it * 1024]], 1);
  __syncthreads();
  if (t < 16) {
    int s = 0;
#pragma unroll
    for (int x = 0; x < 16; ++x) s += sh[x][t];
    hist_s[t] = s;
  }
  __syncthreads();

  int i = blockIdx.x * 1024 + t;
  float st = 0.f, sp = 0.f, sa = 0.f;
#pragma unroll
  for (int cs = 0; cs < CS; ++cs) {
    const float* p = P + ((size_t)cs * NROWS + i) * 3;
    st += p[0]; sp += p[1]; sa += p[2];
  }
  float cnt = (float)hist_s[lab[i]];
  float negtot = st - sp + cnt;  // negatives' E + positives' exp(0)=1 each
  // sum over positives of [log(negtot)+log1p(E/negtot)-sim] ~= cnt*log(negtot)+posE/negtot-ln2*sa
  float li = cnt * logf(negtot) + sp / negtot - LN2F * sa;
  sred[t] = li;
  __syncthreads();
  for (int s2 = 512; s2 > 0; s2 >>= 1) {
    if (t < s2) sred[t] += sred[t + s2];
    __syncthreads();
  }
  if (t == 0) {
    atomicAdd(&losssum[0], sred[0]);
    if (blockIdx.x == 0) {
      int np = 0;
#pragma unroll
      for (int c = 0; c < 10; ++c) np += hist_s[c] * hist_s[c];
      losssum[1] = (float)np;
    }
  }
}

// ---------------- output ----------------
__global__ void k_out(const float* __restrict__ losssum, float* __restrict__ out) {
  if (threadIdx.x == 0) out[0] = losssum[0] / losssum[1];
}

extern "C" void kernel_launch(void* const* d_in, const int* in_sizes, int n_in,
                              void* d_out, int out_size, void* d_ws, size_t ws_size,
                              hipStream_t stream) {
  const float* feat = (const float*)d_in[0];
  const int* lab = (const int*)d_in[1];
  float* out = (float*)d_out;
  char* ws = (char*)d_ws;

  __hip_bfloat16* fnb = (__hip_bfloat16*)ws;                       // 2 MiB
  size_t off = (size_t)NROWS * DIM * 2;
  float* P = (float*)(ws + off); off += (size_t)CS * NROWS * 3 * 4; // 768 KiB
  float* losssum = (float*)(ws + off);

  k_norm<<<NROWS / 4, 256, 0, stream>>>(feat, fnb, losssum);
  k_main<<<dim3(CS, RS), 256, 0, stream>>>((const ushort*)fnb, lab, P);
  k_rowfinal<<<NROWS / 1024, 1024, 0, stream>>>(P, lab, losssum);
  k_out<<<1, 64, 0, stream>>>(losssum, out);
}